// Round 1
// baseline (503.544 us; speedup 1.0000x reference)
//
#include <hip/hip_runtime.h>

// out = mean( (rowdot(x,y) / (||x||_F * ||y||_F) * RAD2DEG)^2 )
// N=65536 rows, D=1024 cols, fp32. Memory-bound: 512 MiB reads.

#define RAD2DEG 57.29577951308232f

constexpr int N_ROWS = 65536;
constexpr int D_COLS = 1024;
constexpr int BLOCKS = 2048;
constexpr int THREADS = 256;
constexpr int WAVES_PER_BLOCK = THREADS / 64;   // 4

// Kernel 1: per-block partials {sum(dot^2), sum(x^2), sum(y^2)} -> d_ws
__global__ __launch_bounds__(THREADS) void ang_partials(
        const float* __restrict__ x,
        const float* __restrict__ y,
        float* __restrict__ partials) {
    const int lane  = threadIdx.x & 63;
    const int wid   = threadIdx.x >> 6;
    const int gwave = blockIdx.x * WAVES_PER_BLOCK + wid;
    const int nwave = gridDim.x * WAVES_PER_BLOCK;   // 8192 -> 8 rows/wave

    float x2 = 0.0f, y2 = 0.0f, dsq = 0.0f;

    for (int row = gwave; row < N_ROWS; row += nwave) {
        const float4* __restrict__ xr = (const float4*)(x + (size_t)row * D_COLS);
        const float4* __restrict__ yr = (const float4*)(y + (size_t)row * D_COLS);
        float dot = 0.0f;
#pragma unroll
        for (int k = 0; k < 4; ++k) {
            float4 a = xr[lane + 64 * k];   // coalesced: 64 lanes x 16B = 1KiB
            float4 b = yr[lane + 64 * k];
            dot = fmaf(a.x, b.x, dot);
            dot = fmaf(a.y, b.y, dot);
            dot = fmaf(a.z, b.z, dot);
            dot = fmaf(a.w, b.w, dot);
            x2  = fmaf(a.x, a.x, x2);
            x2  = fmaf(a.y, a.y, x2);
            x2  = fmaf(a.z, a.z, x2);
            x2  = fmaf(a.w, a.w, x2);
            y2  = fmaf(b.x, b.x, y2);
            y2  = fmaf(b.y, b.y, y2);
            y2  = fmaf(b.z, b.z, y2);
            y2  = fmaf(b.w, b.w, y2);
        }
        // butterfly reduce dot across the 64-lane wave
#pragma unroll
        for (int off = 32; off > 0; off >>= 1)
            dot += __shfl_xor(dot, off, 64);
        // all lanes now hold the same full row dot
        dsq = fmaf(dot, dot, dsq);
    }

    // reduce x2/y2 across the wave (dsq already wave-uniform)
#pragma unroll
    for (int off = 32; off > 0; off >>= 1) {
        x2 += __shfl_xor(x2, off, 64);
        y2 += __shfl_xor(y2, off, 64);
    }

    __shared__ float s[WAVES_PER_BLOCK][3];
    if (lane == 0) {
        s[wid][0] = dsq;
        s[wid][1] = x2;
        s[wid][2] = y2;
    }
    __syncthreads();
    if (threadIdx.x == 0) {
        float a = 0.0f, b = 0.0f, c = 0.0f;
#pragma unroll
        for (int w = 0; w < WAVES_PER_BLOCK; ++w) {
            a += s[w][0];
            b += s[w][1];
            c += s[w][2];
        }
        partials[blockIdx.x * 3 + 0] = a;
        partials[blockIdx.x * 3 + 1] = b;
        partials[blockIdx.x * 3 + 2] = c;
    }
}

// Kernel 2: reduce 2048 block-partials, emit the scalar.
__global__ __launch_bounds__(256) void ang_final(
        const float* __restrict__ partials,
        float* __restrict__ out,
        int nblocks) {
    const int lane = threadIdx.x & 63;
    const int wid  = threadIdx.x >> 6;

    float a = 0.0f, b = 0.0f, c = 0.0f;
    for (int i = threadIdx.x; i < nblocks; i += 256) {
        a += partials[i * 3 + 0];
        b += partials[i * 3 + 1];
        c += partials[i * 3 + 2];
    }
#pragma unroll
    for (int off = 32; off > 0; off >>= 1) {
        a += __shfl_xor(a, off, 64);
        b += __shfl_xor(b, off, 64);
        c += __shfl_xor(c, off, 64);
    }
    __shared__ float s[4][3];
    if (lane == 0) {
        s[wid][0] = a;
        s[wid][1] = b;
        s[wid][2] = c;
    }
    __syncthreads();
    if (threadIdx.x == 0) {
        float ta = 0.0f, tb = 0.0f, tc = 0.0f;
#pragma unroll
        for (int w = 0; w < 4; ++w) {
            ta += s[w][0];
            tb += s[w][1];
            tc += s[w][2];
        }
        // mean(dif_ang^2) = sum(dot^2) / (sumx2 * sumy2) * RAD2DEG^2 / N
        out[0] = ta / (tb * tc) * (RAD2DEG * RAD2DEG / (float)N_ROWS);
    }
}

extern "C" void kernel_launch(void* const* d_in, const int* in_sizes, int n_in,
                              void* d_out, int out_size, void* d_ws, size_t ws_size,
                              hipStream_t stream) {
    const float* x = (const float*)d_in[0];
    const float* y = (const float*)d_in[1];
    float* out = (float*)d_out;
    float* partials = (float*)d_ws;   // BLOCKS*3 floats = 24 KiB

    ang_partials<<<BLOCKS, THREADS, 0, stream>>>(x, y, partials);
    ang_final<<<1, 256, 0, stream>>>(partials, out, BLOCKS);
}